// Round 2
// baseline (523.346 us; speedup 1.0000x reference)
//
#include <hip/hip_runtime.h>

#define NN 10000
#define NE 160000
#define NH 32
#define LRELU_SLOPE 0.2f
#define SM_EPS 1e-16f

// ---------------- edge dtype detect + normalize ----------------
// int64 little-endian node ids (< 2^31) look like [value, 0] u32 pairs.
__global__ void k_edge_detect(const unsigned int* __restrict__ raw, int* __restrict__ flag) {
    if (threadIdx.x == 0 && blockIdx.x == 0) {
        int z = 1;
        for (int i = 1; i < 32; i += 2) z &= (raw[i] == 0u);
        *flag = z;   // 1 => int64
    }
}
__global__ void k_edge_norm(const int* __restrict__ raw, const int* __restrict__ flag,
                            int* __restrict__ srcv, int* __restrict__ dstv) {
    int e = blockIdx.x * blockDim.x + threadIdx.x;
    if (e >= NE) return;
    if (*flag) { srcv[e] = raw[2 * e]; dstv[e] = raw[2 * (NE + e)]; }
    else       { srcv[e] = raw[e];     dstv[e] = raw[NE + e]; }
}

// ---------------- CSR build ----------------
__global__ void k_zero(int* p, int n) {
    int i = blockIdx.x * blockDim.x + threadIdx.x;
    if (i < n) p[i] = 0;
}
__global__ void k_hist(const int* __restrict__ dstv, int* __restrict__ deg) {
    int e = blockIdx.x * blockDim.x + threadIdx.x;
    if (e < NE) atomicAdd(&deg[dstv[e]], 1);
}
__global__ void k_scan(const int* __restrict__ deg, int* __restrict__ offs, int* __restrict__ cursor) {
    __shared__ int sm[1024];
    __shared__ int base;
    int tid = threadIdx.x;
    if (tid == 0) base = 0;
    __syncthreads();
    for (int chunk = 0; chunk < NN; chunk += 1024) {
        int idx = chunk + tid;
        int v = (idx < NN) ? deg[idx] : 0;
        sm[tid] = v; __syncthreads();
        for (int off = 1; off < 1024; off <<= 1) {
            int t = (tid >= off) ? sm[tid - off] : 0;
            __syncthreads();
            sm[tid] += t;
            __syncthreads();
        }
        int excl = sm[tid] - v + base;
        if (idx < NN) { offs[idx] = excl; cursor[idx] = excl; }
        __syncthreads();
        if (tid == 0) base += sm[1023];
        __syncthreads();
    }
    if (tid == 0) offs[NN] = base;
}
__global__ void k_scatter(const int* __restrict__ dstv, int* __restrict__ cursor, int* __restrict__ eid) {
    int e = blockIdx.x * blockDim.x + threadIdx.x;
    if (e < NE) {
        int p = atomicAdd(&cursor[dstv[e]], 1);
        eid[p] = e;
    }
}

// ---------------- GEMM: XP[n, M] = X[n, :K] @ W[K, M]  (all f32) ----------------
template<int K, int M, int TN>
__global__ void k_gemm(const float* __restrict__ X, int ldx, const float* __restrict__ W,
                       float* __restrict__ XP) {
    __shared__ float xs[TN][K];
    const int NT = M / 8;           // blockDim.x
    const int tid = threadIdx.x;
    const int nb = blockIdx.x * TN;
    for (int i = tid; i < TN * K; i += NT) {
        int nn = i / K, k = i - nn * K;
        int node = nb + nn;
        xs[nn][k] = (node < NN) ? X[(size_t)node * ldx + k] : 0.f;
    }
    __syncthreads();
    const int m0 = tid * 8;
    float acc[TN][8];
    #pragma unroll
    for (int a = 0; a < TN; a++)
        #pragma unroll
        for (int b = 0; b < 8; b++) acc[a][b] = 0.f;
    #pragma unroll 4
    for (int k = 0; k < K; k++) {
        float4 w0 = *reinterpret_cast<const float4*>(&W[k * M + m0]);
        float4 w1 = *reinterpret_cast<const float4*>(&W[k * M + m0 + 4]);
        float w[8] = {w0.x, w0.y, w0.z, w0.w, w1.x, w1.y, w1.z, w1.w};
        #pragma unroll
        for (int a = 0; a < TN; a++) {
            float xv = xs[a][k];
            #pragma unroll
            for (int b = 0; b < 8; b++) acc[a][b] = fmaf(xv, w[b], acc[a][b]);
        }
    }
    #pragma unroll
    for (int a = 0; a < TN; a++) {
        int node = nb + a;
        if (node < NN) {
            float* dst = &XP[(size_t)node * M + m0];
            *reinterpret_cast<float4*>(dst)     = make_float4(acc[a][0], acc[a][1], acc[a][2], acc[a][3]);
            *reinterpret_cast<float4*>(dst + 4) = make_float4(acc[a][4], acc[a][5], acc[a][6], acc[a][7]);
        }
    }
}

// ---------------- alpha_s / alpha_d ----------------
template<int C>
__global__ void k_alpha(const float* __restrict__ XP, const float* __restrict__ Asrc,
                        const float* __restrict__ Adst, float* __restrict__ aS, float* __restrict__ aD) {
    const int M = NH * C;
    __shared__ float sa[NH * C], sd[NH * C];
    for (int i = threadIdx.x; i < M; i += blockDim.x) {
        sa[i] = Asrc[i];
        sd[i] = Adst[i];
    }
    __syncthreads();
    int idx = blockIdx.x * blockDim.x + threadIdx.x;  // n*NH + h, exact multiple
    int n = idx / NH, h = idx - n * NH;
    const float* row = XP + (size_t)n * M + h * C;
    const float* pa = &sa[h * C];
    const float* pd = &sd[h * C];
    float s1 = 0.f, s2 = 0.f;
    #pragma unroll
    for (int c = 0; c < C; c += 4) {
        float4 xv = *reinterpret_cast<const float4*>(&row[c]);
        s1 = fmaf(xv.x, pa[c+0], s1); s2 = fmaf(xv.x, pd[c+0], s2);
        s1 = fmaf(xv.y, pa[c+1], s1); s2 = fmaf(xv.y, pd[c+1], s2);
        s1 = fmaf(xv.z, pa[c+2], s1); s2 = fmaf(xv.z, pd[c+2], s2);
        s1 = fmaf(xv.w, pa[c+3], s1); s2 = fmaf(xv.w, pd[c+3], s2);
    }
    aS[idx] = s1; aD[idx] = s2;
}

// ---------------- per-dst softmax (1 wave per node) ----------------
__global__ void k_softmax(const float* __restrict__ aS, const float* __restrict__ aD,
                          const int* __restrict__ offs, const int* __restrict__ eid,
                          const int* __restrict__ srcv,
                          float* __restrict__ alphaE, float* __restrict__ rden) {
    int wave = threadIdx.x >> 6;
    int lane = threadIdx.x & 63;
    int node = blockIdx.x * 4 + wave;   // 2500*4 == NN exactly
    int h = lane & 31, half = lane >> 5;
    int beg = offs[node], end = offs[node + 1];
    float ad = aD[node * NH + h];
    float m = -1e30f;
    for (int i = beg + half; i < end; i += 2) {
        int e = eid[i];
        float sc = aS[srcv[e] * NH + h] + ad;
        sc = (sc >= 0.f) ? sc : LRELU_SLOPE * sc;
        m = fmaxf(m, sc);
    }
    m = fmaxf(m, __shfl_xor(m, 32));
    float ssum = 0.f;
    for (int i = beg + half; i < end; i += 2) {
        int e = eid[i];
        float sc = aS[srcv[e] * NH + h] + ad;
        sc = (sc >= 0.f) ? sc : LRELU_SLOPE * sc;
        float p = expf(sc - m);
        alphaE[(size_t)e * NH + h] = p;
        ssum += p;
    }
    ssum += __shfl_xor(ssum, 32);
    if (half == 0) rden[node * NH + h] = 1.f / (ssum + SM_EPS);
}

// ---------------- aggregation + head-mean + bias + ELU ----------------
template<int C, int VEC>
__global__ void k_agg(const float* __restrict__ XP, const float* __restrict__ alphaE,
                      const float* __restrict__ rden, const int* __restrict__ offs,
                      const int* __restrict__ eid, const int* __restrict__ srcv,
                      const float* __restrict__ bias, float* __restrict__ out, int col0) {
    const int M = NH * C;
    const int tid = threadIdx.x;        // blockDim = M/VEC = 256
    const int node = blockIdx.x;
    const int m0 = tid * VEC;
    const int h = m0 / C;
    const int beg = offs[node], end = offs[node + 1];
    float acc[VEC];
    #pragma unroll
    for (int j = 0; j < VEC; j++) acc[j] = 0.f;
    for (int i = beg; i < end; i++) {
        int e = eid[i];
        int s = srcv[e];
        float a = alphaE[(size_t)e * NH + h];
        const float* row = &XP[(size_t)s * M + m0];
        if constexpr (VEC == 8) {
            float4 v0 = *reinterpret_cast<const float4*>(row);
            float4 v1 = *reinterpret_cast<const float4*>(row + 4);
            acc[0] = fmaf(a, v0.x, acc[0]); acc[1] = fmaf(a, v0.y, acc[1]);
            acc[2] = fmaf(a, v0.z, acc[2]); acc[3] = fmaf(a, v0.w, acc[3]);
            acc[4] = fmaf(a, v1.x, acc[4]); acc[5] = fmaf(a, v1.y, acc[5]);
            acc[6] = fmaf(a, v1.z, acc[6]); acc[7] = fmaf(a, v1.w, acc[7]);
        } else {
            float4 v0 = *reinterpret_cast<const float4*>(row);
            acc[0] = fmaf(a, v0.x, acc[0]); acc[1] = fmaf(a, v0.y, acc[1]);
            acc[2] = fmaf(a, v0.z, acc[2]); acc[3] = fmaf(a, v0.w, acc[3]);
        }
    }
    float r = rden[node * NH + h];
    __shared__ float red[NH * C];
    #pragma unroll
    for (int j = 0; j < VEC; j++) red[m0 + j] = acc[j] * r;
    __syncthreads();
    if (tid < C) {
        float sres = 0.f;
        #pragma unroll 8
        for (int hh = 0; hh < NH; hh++) sres += red[hh * C + tid];
        sres = sres * (1.0f / NH) + bias[tid];
        sres = (sres > 0.f) ? sres : expm1f(sres);
        out[(size_t)node * 96 + col0 + tid] = sres;
    }
}

extern "C" void kernel_launch(void* const* d_in, const int* in_sizes, int n_in,
                              void* d_out, int out_size, void* d_ws, size_t ws_size,
                              hipStream_t stream) {
    const float* x   = (const float*)d_in[0];
    const int*   ei  = (const int*)d_in[1];
    const float* W1  = (const float*)d_in[2];
    const float* as1 = (const float*)d_in[3];
    const float* ad1 = (const float*)d_in[4];
    const float* b1  = (const float*)d_in[5];
    const float* W2  = (const float*)d_in[6];
    const float* as2 = (const float*)d_in[7];
    const float* ad2 = (const float*)d_in[8];
    const float* b2  = (const float*)d_in[9];
    float* out = (float*)d_out;

    char* w = (char*)d_ws;
    size_t off = 0;
    auto alloc = [&](size_t bytes) -> void* {
        void* p = w + off;
        off = (off + bytes + 255) & ~(size_t)255;
        return p;
    };
    float* xp     = (float*)alloc((size_t)NN * 2048 * 4);   // reused for layer2 (smaller)
    float* aS     = (float*)alloc((size_t)NN * NH * 4);
    float* aD     = (float*)alloc((size_t)NN * NH * 4);
    float* alphaE = (float*)alloc((size_t)NE * NH * 4);
    float* rden   = (float*)alloc((size_t)NN * NH * 4);
    int*   deg    = (int*)alloc((size_t)NN * 4);
    int*   cursor = (int*)alloc((size_t)NN * 4);
    int*   offs   = (int*)alloc((size_t)(NN + 1) * 4);
    int*   eid    = (int*)alloc((size_t)NE * 4);
    int*   srcv   = (int*)alloc((size_t)NE * 4);
    int*   dstv   = (int*)alloc((size_t)NE * 4);
    int*   eflag  = (int*)alloc(256);
    (void)ws_size; (void)in_sizes; (void)n_in; (void)out_size;

    // normalize edges (handles int32 or int64 on-device), then CSR by destination
    k_edge_detect<<<1, 64, 0, stream>>>((const unsigned int*)ei, eflag);
    k_edge_norm<<<(NE + 255) / 256, 256, 0, stream>>>(ei, eflag, srcv, dstv);
    k_zero<<<(NN + 255) / 256, 256, 0, stream>>>(deg, NN);
    k_hist<<<NE / 256, 256, 0, stream>>>(dstv, deg);
    k_scan<<<1, 1024, 0, stream>>>(deg, offs, cursor);
    k_scatter<<<NE / 256, 256, 0, stream>>>(dstv, cursor, eid);

    // ---- Layer 1: K=128, C=64, M=2048 ----
    k_gemm<128, 2048, 8><<<(NN + 7) / 8, 256, 0, stream>>>(x, 128, W1, xp);
    k_alpha<64><<<(NN * NH) / 256, 256, 0, stream>>>(xp, as1, ad1, aS, aD);
    k_softmax<<<NN / 4, 256, 0, stream>>>(aS, aD, offs, eid, srcv, alphaE, rden);
    k_agg<64, 8><<<NN, 256, 0, stream>>>(xp, alphaE, rden, offs, eid, srcv, b1, out, 0);

    // ---- Layer 2: K=64 (z1 rows strided by 96 in d_out), C=32, M=1024 ----
    k_gemm<64, 1024, 8><<<(NN + 7) / 8, 128, 0, stream>>>(out, 96, W2, xp);
    k_alpha<32><<<(NN * NH) / 256, 256, 0, stream>>>(xp, as2, ad2, aS, aD);
    k_softmax<<<NN / 4, 256, 0, stream>>>(aS, aD, offs, eid, srcv, alphaE, rden);
    k_agg<32, 4><<<NN, 256, 0, stream>>>(xp, alphaE, rden, offs, eid, srcv, b2, out, 64);
}

// Round 3
// 365.546 us; speedup vs baseline: 1.4317x; 1.4317x over previous
//
#include <hip/hip_runtime.h>
#include <hip/hip_bf16.h>

#define NN 10000
#define NE 160000
#define NH 32
#define LRELU_SLOPE 0.2f
#define SM_EPS 1e-16f

typedef __hip_bfloat16 bf16;

__device__ __forceinline__ float bits2f(unsigned int u16) {
    union { unsigned int u; float f; } v; v.u = u16 << 16; return v.f;
}
template<int VEC>
__device__ __forceinline__ void loadbf(const bf16* __restrict__ p, float f[VEC]) {
    if constexpr (VEC == 8) {
        uint4 v = *reinterpret_cast<const uint4*>(p);
        f[0] = bits2f(v.x & 0xffffu); f[1] = bits2f(v.x >> 16);
        f[2] = bits2f(v.y & 0xffffu); f[3] = bits2f(v.y >> 16);
        f[4] = bits2f(v.z & 0xffffu); f[5] = bits2f(v.z >> 16);
        f[6] = bits2f(v.w & 0xffffu); f[7] = bits2f(v.w >> 16);
    } else {
        uint2 v = *reinterpret_cast<const uint2*>(p);
        f[0] = bits2f(v.x & 0xffffu); f[1] = bits2f(v.x >> 16);
        f[2] = bits2f(v.y & 0xffffu); f[3] = bits2f(v.y >> 16);
    }
}

// ---------------- edge dtype detect + normalize ----------------
__global__ void k_edge_detect(const unsigned int* __restrict__ raw, int* __restrict__ flag) {
    if (threadIdx.x == 0 && blockIdx.x == 0) {
        int z = 1;
        for (int i = 1; i < 32; i += 2) z &= (raw[i] == 0u);
        *flag = z;   // 1 => int64
    }
}
__global__ void k_edge_norm(const int* __restrict__ raw, const int* __restrict__ flag,
                            int* __restrict__ srcv, int* __restrict__ dstv) {
    int e = blockIdx.x * blockDim.x + threadIdx.x;
    if (e >= NE) return;
    if (*flag) { srcv[e] = raw[2 * e]; dstv[e] = raw[2 * (NE + e)]; }
    else       { srcv[e] = raw[e];     dstv[e] = raw[NE + e]; }
}

// ---------------- CSR build ----------------
__global__ void k_zero(int* p, int n) {
    int i = blockIdx.x * blockDim.x + threadIdx.x;
    if (i < n) p[i] = 0;
}
__global__ void k_hist(const int* __restrict__ dstv, int* __restrict__ deg) {
    int e = blockIdx.x * blockDim.x + threadIdx.x;
    if (e < NE) atomicAdd(&deg[dstv[e]], 1);
}
__global__ void k_scan(const int* __restrict__ deg, int* __restrict__ offs, int* __restrict__ cursor) {
    __shared__ int sm[1024];
    __shared__ int base;
    int tid = threadIdx.x;
    if (tid == 0) base = 0;
    __syncthreads();
    for (int chunk = 0; chunk < NN; chunk += 1024) {
        int idx = chunk + tid;
        int v = (idx < NN) ? deg[idx] : 0;
        sm[tid] = v; __syncthreads();
        for (int off = 1; off < 1024; off <<= 1) {
            int t = (tid >= off) ? sm[tid - off] : 0;
            __syncthreads();
            sm[tid] += t;
            __syncthreads();
        }
        int excl = sm[tid] - v + base;
        if (idx < NN) { offs[idx] = excl; cursor[idx] = excl; }
        __syncthreads();
        if (tid == 0) base += sm[1023];
        __syncthreads();
    }
    if (tid == 0) offs[NN] = base;
}
// stores CSR-ordered source list directly (no eid indirection downstream)
__global__ void k_scatter(const int* __restrict__ srcv, const int* __restrict__ dstv,
                          int* __restrict__ cursor, int* __restrict__ srcs) {
    int e = blockIdx.x * blockDim.x + threadIdx.x;
    if (e < NE) {
        int p = atomicAdd(&cursor[dstv[e]], 1);
        srcs[p] = srcv[e];
    }
}

// ------- GEMM: XPB[n, M](bf16) = X[n, :K] @ W[K, M]; fused alpha dot-products -------
template<int K, int M, int C, int TN>
__global__ void k_gemm(const float* __restrict__ X, int ldx, const float* __restrict__ W,
                       const float* __restrict__ Asrc, const float* __restrict__ Adst,
                       bf16* __restrict__ XPB, float* __restrict__ aS, float* __restrict__ aD) {
    __shared__ float xs[TN][K];
    const int NT = M / 8;           // blockDim.x
    const int GROUP = C / 8;        // threads per head
    const int tid = threadIdx.x;
    const int nb = blockIdx.x * TN;
    // per-thread attention vector slices (layout matches m0 exactly)
    const int m0 = tid * 8;
    float ar[8], adr[8];
    *reinterpret_cast<float4*>(ar)      = *reinterpret_cast<const float4*>(&Asrc[m0]);
    *reinterpret_cast<float4*>(ar + 4)  = *reinterpret_cast<const float4*>(&Asrc[m0 + 4]);
    *reinterpret_cast<float4*>(adr)     = *reinterpret_cast<const float4*>(&Adst[m0]);
    *reinterpret_cast<float4*>(adr + 4) = *reinterpret_cast<const float4*>(&Adst[m0 + 4]);

    for (int i = tid; i < TN * K; i += NT) {
        int nn = i / K, k = i - nn * K;
        int node = nb + nn;
        xs[nn][k] = (node < NN) ? X[(size_t)node * ldx + k] : 0.f;
    }
    __syncthreads();
    float acc[TN][8];
    #pragma unroll
    for (int a = 0; a < TN; a++)
        #pragma unroll
        for (int b = 0; b < 8; b++) acc[a][b] = 0.f;
    #pragma unroll 4
    for (int k = 0; k < K; k++) {
        float4 w0 = *reinterpret_cast<const float4*>(&W[k * M + m0]);
        float4 w1 = *reinterpret_cast<const float4*>(&W[k * M + m0 + 4]);
        float w[8] = {w0.x, w0.y, w0.z, w0.w, w1.x, w1.y, w1.z, w1.w};
        #pragma unroll
        for (int a = 0; a < TN; a++) {
            float xv = xs[a][k];
            #pragma unroll
            for (int b = 0; b < 8; b++) acc[a][b] = fmaf(xv, w[b], acc[a][b]);
        }
    }
    const int h = m0 / C;
    #pragma unroll
    for (int a = 0; a < TN; a++) {
        int node = nb + a;
        if (node >= NN) continue;       // uniform across block
        bf16 hs[8];
        #pragma unroll
        for (int b = 0; b < 8; b++) hs[b] = __float2bfloat16(acc[a][b]);
        *reinterpret_cast<uint4*>(&XPB[(size_t)node * M + m0]) =
            *reinterpret_cast<const uint4*>(hs);
        float ps = 0.f, pd = 0.f;
        #pragma unroll
        for (int b = 0; b < 8; b++) {
            ps = fmaf(acc[a][b], ar[b], ps);
            pd = fmaf(acc[a][b], adr[b], pd);
        }
        #pragma unroll
        for (int wdt = 1; wdt < GROUP; wdt <<= 1) {
            ps += __shfl_xor(ps, wdt);
            pd += __shfl_xor(pd, wdt);
        }
        if ((tid & (GROUP - 1)) == 0) {
            aS[node * NH + h] = ps;
            aD[node * NH + h] = pd;
        }
    }
}

// ---------------- per-dst softmax (1 wave per node), CSR-ordered output ----------------
__global__ void k_softmax(const float* __restrict__ aS, const float* __restrict__ aD,
                          const int* __restrict__ offs, const int* __restrict__ srcs,
                          float* __restrict__ alphaE, float* __restrict__ rden) {
    int wave = threadIdx.x >> 6;
    int lane = threadIdx.x & 63;
    int node = blockIdx.x * 4 + wave;   // 2500*4 == NN exactly
    int h = lane & 31, half = lane >> 5;
    int beg = offs[node], end = offs[node + 1];
    float ad = aD[node * NH + h];
    float m = -1e30f;
    for (int i = beg + half; i < end; i += 2) {
        float sc = aS[srcs[i] * NH + h] + ad;
        sc = (sc >= 0.f) ? sc : LRELU_SLOPE * sc;
        m = fmaxf(m, sc);
    }
    m = fmaxf(m, __shfl_xor(m, 32));
    float ssum = 0.f;
    for (int i = beg + half; i < end; i += 2) {
        float sc = aS[srcs[i] * NH + h] + ad;
        sc = (sc >= 0.f) ? sc : LRELU_SLOPE * sc;
        float p = expf(sc - m);
        alphaE[(size_t)i * NH + h] = p;    // CSR position order
        ssum += p;
    }
    ssum += __shfl_xor(ssum, 32);
    if (half == 0) rden[node * NH + h] = 1.f / (ssum + SM_EPS);
}

// ---------------- aggregation + head-mean + bias + ELU ----------------
template<int C, int VEC>
__global__ void k_agg(const bf16* __restrict__ XPB, const float* __restrict__ alphaE,
                      const float* __restrict__ rden, const int* __restrict__ offs,
                      const int* __restrict__ srcs,
                      const float* __restrict__ bias, float* __restrict__ out, int col0) {
    const int M = NH * C;
    const int tid = threadIdx.x;        // blockDim = M/VEC = 256
    const int node = blockIdx.x;
    const int m0 = tid * VEC;
    const int h = m0 / C;
    const int beg = offs[node], end = offs[node + 1];
    float acc[VEC];
    #pragma unroll
    for (int j = 0; j < VEC; j++) acc[j] = 0.f;
    int i = beg;
    for (; i + 4 <= end; i += 4) {
        int s0 = srcs[i], s1 = srcs[i + 1], s2 = srcs[i + 2], s3 = srcs[i + 3];
        float a0 = alphaE[(size_t)(i    ) * NH + h];
        float a1 = alphaE[(size_t)(i + 1) * NH + h];
        float a2 = alphaE[(size_t)(i + 2) * NH + h];
        float a3 = alphaE[(size_t)(i + 3) * NH + h];
        float x0[VEC], x1[VEC], x2[VEC], x3[VEC];
        loadbf<VEC>(&XPB[(size_t)s0 * M + m0], x0);
        loadbf<VEC>(&XPB[(size_t)s1 * M + m0], x1);
        loadbf<VEC>(&XPB[(size_t)s2 * M + m0], x2);
        loadbf<VEC>(&XPB[(size_t)s3 * M + m0], x3);
        #pragma unroll
        for (int j = 0; j < VEC; j++) {
            acc[j] = fmaf(a0, x0[j], acc[j]);
            acc[j] = fmaf(a1, x1[j], acc[j]);
            acc[j] = fmaf(a2, x2[j], acc[j]);
            acc[j] = fmaf(a3, x3[j], acc[j]);
        }
    }
    for (; i < end; i++) {
        int s = srcs[i];
        float a = alphaE[(size_t)i * NH + h];
        float xv[VEC];
        loadbf<VEC>(&XPB[(size_t)s * M + m0], xv);
        #pragma unroll
        for (int j = 0; j < VEC; j++) acc[j] = fmaf(a, xv[j], acc[j]);
    }
    float r = rden[node * NH + h];
    __shared__ float red[NH * C];
    #pragma unroll
    for (int j = 0; j < VEC; j++) red[m0 + j] = acc[j] * r;
    __syncthreads();
    if (tid < C) {
        float sres = 0.f;
        #pragma unroll 8
        for (int hh = 0; hh < NH; hh++) sres += red[hh * C + tid];
        sres = sres * (1.0f / NH) + bias[tid];
        sres = (sres > 0.f) ? sres : expm1f(sres);
        out[(size_t)node * 96 + col0 + tid] = sres;
    }
}

extern "C" void kernel_launch(void* const* d_in, const int* in_sizes, int n_in,
                              void* d_out, int out_size, void* d_ws, size_t ws_size,
                              hipStream_t stream) {
    const float* x   = (const float*)d_in[0];
    const int*   ei  = (const int*)d_in[1];
    const float* W1  = (const float*)d_in[2];
    const float* as1 = (const float*)d_in[3];
    const float* ad1 = (const float*)d_in[4];
    const float* b1  = (const float*)d_in[5];
    const float* W2  = (const float*)d_in[6];
    const float* as2 = (const float*)d_in[7];
    const float* ad2 = (const float*)d_in[8];
    const float* b2  = (const float*)d_in[9];
    float* out = (float*)d_out;

    char* w = (char*)d_ws;
    size_t off = 0;
    auto alloc = [&](size_t bytes) -> void* {
        void* p = w + off;
        off = (off + bytes + 255) & ~(size_t)255;
        return p;
    };
    bf16*  xpb    = (bf16*)alloc((size_t)NN * 2048 * 2);    // reused for layer2
    float* aS     = (float*)alloc((size_t)NN * NH * 4);
    float* aD     = (float*)alloc((size_t)NN * NH * 4);
    float* alphaE = (float*)alloc((size_t)NE * NH * 4);
    float* rden   = (float*)alloc((size_t)NN * NH * 4);
    int*   deg    = (int*)alloc((size_t)NN * 4);
    int*   cursor = (int*)alloc((size_t)NN * 4);
    int*   offs   = (int*)alloc((size_t)(NN + 1) * 4);
    int*   srcs   = (int*)alloc((size_t)NE * 4);
    int*   srcv   = (int*)alloc((size_t)NE * 4);
    int*   dstv   = (int*)alloc((size_t)NE * 4);
    int*   eflag  = (int*)alloc(256);
    (void)ws_size; (void)in_sizes; (void)n_in; (void)out_size;

    k_edge_detect<<<1, 64, 0, stream>>>((const unsigned int*)ei, eflag);
    k_edge_norm<<<(NE + 255) / 256, 256, 0, stream>>>(ei, eflag, srcv, dstv);
    k_zero<<<(NN + 255) / 256, 256, 0, stream>>>(deg, NN);
    k_hist<<<NE / 256, 256, 0, stream>>>(dstv, deg);
    k_scan<<<1, 1024, 0, stream>>>(deg, offs, cursor);
    k_scatter<<<NE / 256, 256, 0, stream>>>(srcv, dstv, cursor, srcs);

    // ---- Layer 1: K=128, C=64, M=2048 ----
    k_gemm<128, 2048, 64, 8><<<(NN + 7) / 8, 256, 0, stream>>>(x, 128, W1, as1, ad1, xpb, aS, aD);
    k_softmax<<<NN / 4, 256, 0, stream>>>(aS, aD, offs, srcs, alphaE, rden);
    k_agg<64, 8><<<NN, 256, 0, stream>>>(xpb, alphaE, rden, offs, srcs, b1, out, 0);

    // ---- Layer 2: K=64 (z1 rows strided by 96 in d_out), C=32, M=1024 ----
    k_gemm<64, 1024, 32, 8><<<(NN + 7) / 8, 128, 0, stream>>>(out, 96, W2, as2, ad2, xpb, aS, aD);
    k_softmax<<<NN / 4, 256, 0, stream>>>(aS, aD, offs, srcs, alphaE, rden);
    k_agg<32, 4><<<NN, 256, 0, stream>>>(xpb, alphaE, rden, offs, srcs, b2, out, 64);
}

// Round 4
// 279.039 us; speedup vs baseline: 1.8755x; 1.3100x over previous
//
#include <hip/hip_runtime.h>
#include <hip/hip_bf16.h>

#define NN 10000
#define NE 160000
#define NH 32
#define LRELU_SLOPE 0.2f
#define SM_EPS 1e-16f

typedef __hip_bfloat16 bf16;
typedef __attribute__((ext_vector_type(8))) __bf16 bf16x8;
typedef __attribute__((ext_vector_type(4))) float f32x4;

__device__ __forceinline__ float bits2f(unsigned int u16) {
    union { unsigned int u; float f; } v; v.u = u16 << 16; return v.f;
}
template<int VEC>
__device__ __forceinline__ void loadbf(const bf16* __restrict__ p, float f[VEC]) {
    if constexpr (VEC == 8) {
        uint4 v = *reinterpret_cast<const uint4*>(p);
        f[0] = bits2f(v.x & 0xffffu); f[1] = bits2f(v.x >> 16);
        f[2] = bits2f(v.y & 0xffffu); f[3] = bits2f(v.y >> 16);
        f[4] = bits2f(v.z & 0xffffu); f[5] = bits2f(v.z >> 16);
        f[6] = bits2f(v.w & 0xffffu); f[7] = bits2f(v.w >> 16);
    } else {
        uint2 v = *reinterpret_cast<const uint2*>(p);
        f[0] = bits2f(v.x & 0xffffu); f[1] = bits2f(v.x >> 16);
        f[2] = bits2f(v.y & 0xffffu); f[3] = bits2f(v.y >> 16);
    }
}

// ---------------- edge dtype detect + normalize ----------------
__global__ void k_edge_detect(const unsigned int* __restrict__ raw, int* __restrict__ flag) {
    if (threadIdx.x == 0 && blockIdx.x == 0) {
        int z = 1;
        for (int i = 1; i < 32; i += 2) z &= (raw[i] == 0u);
        *flag = z;   // 1 => int64
    }
}
__global__ void k_edge_norm(const int* __restrict__ raw, const int* __restrict__ flag,
                            int* __restrict__ srcv, int* __restrict__ dstv) {
    int e = blockIdx.x * blockDim.x + threadIdx.x;
    if (e >= NE) return;
    if (*flag) { srcv[e] = raw[2 * e]; dstv[e] = raw[2 * (NE + e)]; }
    else       { srcv[e] = raw[e];     dstv[e] = raw[NE + e]; }
}

// ---------------- CSR build ----------------
__global__ void k_zero(int* p, int n) {
    int i = blockIdx.x * blockDim.x + threadIdx.x;
    if (i < n) p[i] = 0;
}
__global__ void k_hist(const int* __restrict__ dstv, int* __restrict__ deg) {
    int e = blockIdx.x * blockDim.x + threadIdx.x;
    if (e < NE) atomicAdd(&deg[dstv[e]], 1);
}
__global__ void k_scan(const int* __restrict__ deg, int* __restrict__ offs, int* __restrict__ cursor) {
    __shared__ int sm[1024];
    __shared__ int base;
    int tid = threadIdx.x;
    if (tid == 0) base = 0;
    __syncthreads();
    for (int chunk = 0; chunk < NN; chunk += 1024) {
        int idx = chunk + tid;
        int v = (idx < NN) ? deg[idx] : 0;
        sm[tid] = v; __syncthreads();
        for (int off = 1; off < 1024; off <<= 1) {
            int t = (tid >= off) ? sm[tid - off] : 0;
            __syncthreads();
            sm[tid] += t;
            __syncthreads();
        }
        int excl = sm[tid] - v + base;
        if (idx < NN) { offs[idx] = excl; cursor[idx] = excl; }
        __syncthreads();
        if (tid == 0) base += sm[1023];
        __syncthreads();
    }
    if (tid == 0) offs[NN] = base;
}
__global__ void k_scatter(const int* __restrict__ srcv, const int* __restrict__ dstv,
                          int* __restrict__ cursor, int* __restrict__ srcs) {
    int e = blockIdx.x * blockDim.x + threadIdx.x;
    if (e < NE) {
        int p = atomicAdd(&cursor[dstv[e]], 1);
        srcs[p] = srcv[e];
    }
}

// ---------------- precompute: f32 -> bf16 cast, W transpose ----------------
__global__ void k_cast(const float* __restrict__ X, bf16* __restrict__ Xb, int n) {
    int i = blockIdx.x * blockDim.x + threadIdx.x;
    if (i < n) Xb[i] = __float2bfloat16(X[i]);
}
__global__ void k_transpose(const float* __restrict__ W, bf16* __restrict__ Wt, int K, int M) {
    int idx = blockIdx.x * blockDim.x + threadIdx.x;
    if (idx >= K * M) return;
    int k = idx / M, m = idx - k * M;          // consecutive tid -> consecutive m: coalesced read
    Wt[(size_t)m * K + k] = __float2bfloat16(W[idx]);
}

// ------- MFMA GEMM: XPB[n, M](bf16) = Xb[n, :K] @ Wt^T; fused alpha dots -------
// BM=64 rows(nodes), BN=128 cols, 4 waves. Wt is [M][K] (pre-transposed W).
template<int K, int M, int C>
__global__ __launch_bounds__(256) void k_gemm_mfma(
        const bf16* __restrict__ Xb, const bf16* __restrict__ Wt,
        const float* __restrict__ Asrc, const float* __restrict__ Adst,
        bf16* __restrict__ XPB, float* __restrict__ aS, float* __restrict__ aD) {
    constexpr int BM = 64, BN = 128;
    constexpr int KB = K * 2;            // LDS row bytes
    constexpr int NHB = BN / C;          // heads per block (2 or 4)
    constexpr int WPH = C / 32;          // waves per head  (2 or 1)
    __shared__ char lds[(BM + BN) * KB];
    __shared__ float sredS[4][BM], sredD[4][BM];
    char* lA = lds;
    char* lB = lds + BM * KB;

    const int tid = threadIdx.x;
    const int wv = tid >> 6, ln = tid & 63;
    const int lrow = ln & 15, lkb = ln >> 4;
    const int brow = blockIdx.x * BM;
    const int bcol = blockIdx.y * BN;

    // stage A: rows brow..brow+63 of Xb (zero-fill past NN), XOR-swizzled rows
    #pragma unroll
    for (int c = 0; c < BM * K / 8 / 256; c++) {
        int it = c * 256 + tid;
        int r = it / (K / 8), kc = (it % (K / 8)) * 8;
        int node = brow + r;
        uint4 v = make_uint4(0u, 0u, 0u, 0u);
        if (node < NN) v = *reinterpret_cast<const uint4*>(&Xb[(size_t)node * K + kc]);
        *reinterpret_cast<uint4*>(lA + ((r * KB + kc * 2) ^ ((r & 7) << 4))) = v;
    }
    // stage B: rows bcol..bcol+127 of Wt
    #pragma unroll
    for (int c = 0; c < BN * K / 8 / 256; c++) {
        int it = c * 256 + tid;
        int r = it / (K / 8), kc = (it % (K / 8)) * 8;
        uint4 v = *reinterpret_cast<const uint4*>(&Wt[(size_t)(bcol + r) * K + kc]);
        *reinterpret_cast<uint4*>(lB + ((r * KB + kc * 2) ^ ((r & 7) << 4))) = v;
    }
    __syncthreads();

    f32x4 acc[4][2];
    #pragma unroll
    for (int mi = 0; mi < 4; mi++)
        #pragma unroll
        for (int nj = 0; nj < 2; nj++) acc[mi][nj] = (f32x4){0.f, 0.f, 0.f, 0.f};

    #pragma unroll
    for (int ks = 0; ks < K / 32; ks++) {
        const int k0 = ks * 32 + lkb * 8;
        bf16x8 af[4], bfr[2];
        #pragma unroll
        for (int mi = 0; mi < 4; mi++) {
            int r = mi * 16 + lrow;
            af[mi] = *reinterpret_cast<const bf16x8*>(lA + ((r * KB + k0 * 2) ^ ((r & 7) << 4)));
        }
        #pragma unroll
        for (int nj = 0; nj < 2; nj++) {
            int r = wv * 32 + nj * 16 + lrow;
            bfr[nj] = *reinterpret_cast<const bf16x8*>(lB + ((r * KB + k0 * 2) ^ ((r & 7) << 4)));
        }
        #pragma unroll
        for (int mi = 0; mi < 4; mi++)
            #pragma unroll
            for (int nj = 0; nj < 2; nj++)
                acc[mi][nj] = __builtin_amdgcn_mfma_f32_16x16x32_bf16(af[mi], bfr[nj], acc[mi][nj], 0, 0, 0);
    }

    // epilogue: D col = lane&15, row = (lane>>4)*4 + reg  [m89]
    float ar0 = Asrc[bcol + wv * 32 + lrow];
    float ar1 = Asrc[bcol + wv * 32 + 16 + lrow];
    float ad0 = Adst[bcol + wv * 32 + lrow];
    float ad1 = Adst[bcol + wv * 32 + 16 + lrow];

    #pragma unroll
    for (int mi = 0; mi < 4; mi++) {
        #pragma unroll
        for (int r = 0; r < 4; r++) {
            int rowl = mi * 16 + lkb * 4 + r;
            int row = brow + rowl;
            if (row < NN) {
                XPB[(size_t)row * M + bcol + wv * 32 + lrow]      = __float2bfloat16(acc[mi][0][r]);
                XPB[(size_t)row * M + bcol + wv * 32 + 16 + lrow] = __float2bfloat16(acc[mi][1][r]);
            }
            float vs = acc[mi][0][r] * ar0 + acc[mi][1][r] * ar1;
            float vd = acc[mi][0][r] * ad0 + acc[mi][1][r] * ad1;
            vs += __shfl_xor(vs, 1); vd += __shfl_xor(vd, 1);
            vs += __shfl_xor(vs, 2); vd += __shfl_xor(vd, 2);
            vs += __shfl_xor(vs, 4); vd += __shfl_xor(vd, 4);
            vs += __shfl_xor(vs, 8); vd += __shfl_xor(vd, 8);
            if (lrow == 0) {
                sredS[wv][rowl] = vs;
                sredD[wv][rowl] = vd;
            }
        }
    }
    __syncthreads();
    if (tid < BM) {
        int node = brow + tid;
        if (node < NN) {
            #pragma unroll
            for (int hb = 0; hb < NHB; hb++) {
                float ss = 0.f, dd = 0.f;
                #pragma unroll
                for (int w = 0; w < WPH; w++) {
                    ss += sredS[hb * WPH + w][tid];
                    dd += sredD[hb * WPH + w][tid];
                }
                int h = bcol / C + hb;
                aS[node * NH + h] = ss;
                aD[node * NH + h] = dd;
            }
        }
    }
}

// ---------------- per-dst softmax (1 wave per node), CSR-ordered output ----------------
__global__ void k_softmax(const float* __restrict__ aS, const float* __restrict__ aD,
                          const int* __restrict__ offs, const int* __restrict__ srcs,
                          float* __restrict__ alphaE, float* __restrict__ rden) {
    int wave = threadIdx.x >> 6;
    int lane = threadIdx.x & 63;
    int node = blockIdx.x * 4 + wave;   // 2500*4 == NN exactly
    int h = lane & 31, half = lane >> 5;
    int beg = offs[node], end = offs[node + 1];
    float ad = aD[node * NH + h];
    float m = -1e30f;
    for (int i = beg + half; i < end; i += 2) {
        float sc = aS[srcs[i] * NH + h] + ad;
        sc = (sc >= 0.f) ? sc : LRELU_SLOPE * sc;
        m = fmaxf(m, sc);
    }
    m = fmaxf(m, __shfl_xor(m, 32));
    float ssum = 0.f;
    for (int i = beg + half; i < end; i += 2) {
        float sc = aS[srcs[i] * NH + h] + ad;
        sc = (sc >= 0.f) ? sc : LRELU_SLOPE * sc;
        float p = expf(sc - m);
        alphaE[(size_t)i * NH + h] = p;    // CSR position order
        ssum += p;
    }
    ssum += __shfl_xor(ssum, 32);
    if (half == 0) rden[node * NH + h] = 1.f / (ssum + SM_EPS);
}

// ---------------- aggregation + head-mean + bias + ELU (+ bf16 z1 copy) ----------------
template<int C, int VEC, bool WZ>
__global__ void k_agg(const bf16* __restrict__ XPB, const float* __restrict__ alphaE,
                      const float* __restrict__ rden, const int* __restrict__ offs,
                      const int* __restrict__ srcs,
                      const float* __restrict__ bias, float* __restrict__ out, int col0,
                      bf16* __restrict__ z1b) {
    const int M = NH * C;
    const int tid = threadIdx.x;        // blockDim = M/VEC = 256
    const int node = blockIdx.x;
    const int m0 = tid * VEC;
    const int h = m0 / C;
    const int beg = offs[node], end = offs[node + 1];
    float acc[VEC];
    #pragma unroll
    for (int j = 0; j < VEC; j++) acc[j] = 0.f;
    int i = beg;
    for (; i + 4 <= end; i += 4) {
        int s0 = srcs[i], s1 = srcs[i + 1], s2 = srcs[i + 2], s3 = srcs[i + 3];
        float a0 = alphaE[(size_t)(i    ) * NH + h];
        float a1 = alphaE[(size_t)(i + 1) * NH + h];
        float a2 = alphaE[(size_t)(i + 2) * NH + h];
        float a3 = alphaE[(size_t)(i + 3) * NH + h];
        float x0[VEC], x1[VEC], x2[VEC], x3[VEC];
        loadbf<VEC>(&XPB[(size_t)s0 * M + m0], x0);
        loadbf<VEC>(&XPB[(size_t)s1 * M + m0], x1);
        loadbf<VEC>(&XPB[(size_t)s2 * M + m0], x2);
        loadbf<VEC>(&XPB[(size_t)s3 * M + m0], x3);
        #pragma unroll
        for (int j = 0; j < VEC; j++) {
            acc[j] = fmaf(a0, x0[j], acc[j]);
            acc[j] = fmaf(a1, x1[j], acc[j]);
            acc[j] = fmaf(a2, x2[j], acc[j]);
            acc[j] = fmaf(a3, x3[j], acc[j]);
        }
    }
    for (; i < end; i++) {
        int s = srcs[i];
        float a = alphaE[(size_t)i * NH + h];
        float xv[VEC];
        loadbf<VEC>(&XPB[(size_t)s * M + m0], xv);
        #pragma unroll
        for (int j = 0; j < VEC; j++) acc[j] = fmaf(a, xv[j], acc[j]);
    }
    float r = rden[node * NH + h];
    __shared__ float red[NH * C];
    #pragma unroll
    for (int j = 0; j < VEC; j++) red[m0 + j] = acc[j] * r;
    __syncthreads();
    if (tid < C) {
        float sres = 0.f;
        #pragma unroll 8
        for (int hh = 0; hh < NH; hh++) sres += red[hh * C + tid];
        sres = sres * (1.0f / NH) + bias[tid];
        sres = (sres > 0.f) ? sres : expm1f(sres);
        out[(size_t)node * 96 + col0 + tid] = sres;
        if constexpr (WZ) z1b[(size_t)node * C + tid] = __float2bfloat16(sres);
    }
}

extern "C" void kernel_launch(void* const* d_in, const int* in_sizes, int n_in,
                              void* d_out, int out_size, void* d_ws, size_t ws_size,
                              hipStream_t stream) {
    const float* x   = (const float*)d_in[0];
    const int*   ei  = (const int*)d_in[1];
    const float* W1  = (const float*)d_in[2];
    const float* as1 = (const float*)d_in[3];
    const float* ad1 = (const float*)d_in[4];
    const float* b1  = (const float*)d_in[5];
    const float* W2  = (const float*)d_in[6];
    const float* as2 = (const float*)d_in[7];
    const float* ad2 = (const float*)d_in[8];
    const float* b2  = (const float*)d_in[9];
    float* out = (float*)d_out;

    char* w = (char*)d_ws;
    size_t off = 0;
    auto alloc = [&](size_t bytes) -> void* {
        void* p = w + off;
        off = (off + bytes + 255) & ~(size_t)255;
        return p;
    };
    bf16*  xpb    = (bf16*)alloc((size_t)NN * 2048 * 2);    // reused for layer2
    float* aS     = (float*)alloc((size_t)NN * NH * 4);
    float* aD     = (float*)alloc((size_t)NN * NH * 4);
    float* alphaE = (float*)alloc((size_t)NE * NH * 4);
    float* rden   = (float*)alloc((size_t)NN * NH * 4);
    int*   deg    = (int*)alloc((size_t)NN * 4);
    int*   cursor = (int*)alloc((size_t)NN * 4);
    int*   offs   = (int*)alloc((size_t)(NN + 1) * 4);
    int*   srcs   = (int*)alloc((size_t)NE * 4);
    int*   srcv   = (int*)alloc((size_t)NE * 4);
    int*   dstv   = (int*)alloc((size_t)NE * 4);
    bf16*  Xb     = (bf16*)alloc((size_t)NN * 128 * 2);
    bf16*  Wt1    = (bf16*)alloc((size_t)2048 * 128 * 2);
    bf16*  Wt2    = (bf16*)alloc((size_t)1024 * 64 * 2);
    bf16*  z1b    = (bf16*)alloc((size_t)NN * 64 * 2);
    int*   eflag  = (int*)alloc(256);
    (void)ws_size; (void)in_sizes; (void)n_in; (void)out_size;

    // edges + CSR (independent of feature path)
    k_edge_detect<<<1, 64, 0, stream>>>((const unsigned int*)ei, eflag);
    k_edge_norm<<<(NE + 255) / 256, 256, 0, stream>>>(ei, eflag, srcv, dstv);
    k_zero<<<(NN + 255) / 256, 256, 0, stream>>>(deg, NN);
    k_hist<<<NE / 256, 256, 0, stream>>>(dstv, deg);
    k_scan<<<1, 1024, 0, stream>>>(deg, offs, cursor);
    k_scatter<<<NE / 256, 256, 0, stream>>>(srcv, dstv, cursor, srcs);

    // bf16 operand prep
    k_cast<<<(NN * 128 + 255) / 256, 256, 0, stream>>>(x, Xb, NN * 128);
    k_transpose<<<(128 * 2048 + 255) / 256, 256, 0, stream>>>(W1, Wt1, 128, 2048);
    k_transpose<<<(64 * 1024 + 255) / 256, 256, 0, stream>>>(W2, Wt2, 64, 1024);

    // ---- Layer 1: K=128, C=64, M=2048 ----
    k_gemm_mfma<128, 2048, 64><<<dim3((NN + 63) / 64, 2048 / 128), 256, 0, stream>>>(
        Xb, Wt1, as1, ad1, xpb, aS, aD);
    k_softmax<<<NN / 4, 256, 0, stream>>>(aS, aD, offs, srcs, alphaE, rden);
    k_agg<64, 8, true><<<NN, 256, 0, stream>>>(xpb, alphaE, rden, offs, srcs, b1, out, 0, z1b);

    // ---- Layer 2: K=64, C=32, M=1024 ----
    k_gemm_mfma<64, 1024, 32><<<dim3((NN + 63) / 64, 1024 / 128), 256, 0, stream>>>(
        z1b, Wt2, as2, ad2, xpb, aS, aD);
    k_softmax<<<NN / 4, 256, 0, stream>>>(aS, aD, offs, srcs, alphaE, rden);
    k_agg<32, 4, false><<<NN, 256, 0, stream>>>(xpb, alphaE, rden, offs, srcs, b2, out, 64, nullptr);
}

// Round 5
// 232.012 us; speedup vs baseline: 2.2557x; 1.2027x over previous
//
#include <hip/hip_runtime.h>
#include <hip/hip_bf16.h>

#define NN 10000
#define NE 160000
#define NH 32
#define LRELU_SLOPE 0.2f
#define SM_EPS 1e-16f
#define SM_SHIFT 16.0f

typedef __hip_bfloat16 bf16;
typedef __attribute__((ext_vector_type(8))) __bf16 bf16x8;
typedef __attribute__((ext_vector_type(4))) float f32x4;

__device__ __forceinline__ float bits2f(unsigned int u16) {
    union { unsigned int u; float f; } v; v.u = u16 << 16; return v.f;
}
__device__ __forceinline__ void loadbf8(const bf16* __restrict__ p, float f[8]) {
    uint4 v = *reinterpret_cast<const uint4*>(p);
    f[0] = bits2f(v.x & 0xffffu); f[1] = bits2f(v.x >> 16);
    f[2] = bits2f(v.y & 0xffffu); f[3] = bits2f(v.y >> 16);
    f[4] = bits2f(v.z & 0xffffu); f[5] = bits2f(v.z >> 16);
    f[6] = bits2f(v.w & 0xffffu); f[7] = bits2f(v.w >> 16);
}

// ---------------- edge dtype detect + normalize (+ deg zero) ----------------
__global__ void k_edge_detect(const unsigned int* __restrict__ raw, int* __restrict__ flag) {
    if (threadIdx.x == 0 && blockIdx.x == 0) {
        int z = 1;
        for (int i = 1; i < 32; i += 2) z &= (raw[i] == 0u);
        *flag = z;   // 1 => int64
    }
}
__global__ void k_edge_norm(const int* __restrict__ raw, const int* __restrict__ flag,
                            int* __restrict__ srcv, int* __restrict__ dstv, int* __restrict__ deg) {
    int e = blockIdx.x * blockDim.x + threadIdx.x;
    if (e < NN) deg[e] = 0;
    if (e >= NE) return;
    if (*flag) { srcv[e] = raw[2 * e]; dstv[e] = raw[2 * (NE + e)]; }
    else       { srcv[e] = raw[e];     dstv[e] = raw[NE + e]; }
}

// ---------------- CSR build ----------------
__global__ void k_hist(const int* __restrict__ dstv, int* __restrict__ deg) {
    int e = blockIdx.x * blockDim.x + threadIdx.x;
    if (e < NE) atomicAdd(&deg[dstv[e]], 1);
}
// shfl-based scan, 1024 threads, 10 chunks
__global__ void k_scan(const int* __restrict__ deg, int* __restrict__ offs, int* __restrict__ cursor) {
    __shared__ int wsum[16], wpre[16];
    __shared__ int base;
    const int tid = threadIdx.x, lane = tid & 63, wid = tid >> 6;
    if (tid == 0) base = 0;
    __syncthreads();
    for (int chunk = 0; chunk < NN; chunk += 1024) {
        int idx = chunk + tid;
        int v = (idx < NN) ? deg[idx] : 0;
        int s = v;
        #pragma unroll
        for (int off = 1; off < 64; off <<= 1) {
            int t = __shfl_up(s, off);
            if (lane >= off) s += t;
        }
        if (lane == 63) wsum[wid] = s;
        __syncthreads();
        if (wid == 0) {
            int ws = (lane < 16) ? wsum[lane] : 0;
            #pragma unroll
            for (int off = 1; off < 16; off <<= 1) {
                int t = __shfl_up(ws, off);
                if (lane >= off) ws += t;
            }
            if (lane < 16) wpre[lane] = ws;
        }
        __syncthreads();
        int wbase = (wid == 0) ? 0 : wpre[wid - 1];
        int excl = base + wbase + s - v;
        if (idx < NN) { offs[idx] = excl; cursor[idx] = excl; }
        int total = wpre[15];
        __syncthreads();
        if (tid == 0) base += total;
        __syncthreads();
    }
    if (tid == 0) offs[NN] = base;
}
__global__ void k_scatter(const int* __restrict__ srcv, const int* __restrict__ dstv,
                          int* __restrict__ cursor, int* __restrict__ srcs) {
    int e = blockIdx.x * blockDim.x + threadIdx.x;
    if (e < NE) {
        int p = atomicAdd(&cursor[dstv[e]], 1);
        srcs[p] = srcv[e];
    }
}

// ---------------- fused prep: cast X, transpose W1, transpose W2 ----------------
__global__ void k_prep(const float* __restrict__ X, bf16* __restrict__ Xb,
                       const float* __restrict__ W1, bf16* __restrict__ Wt1,
                       const float* __restrict__ W2, bf16* __restrict__ Wt2) {
    int i = blockIdx.x * blockDim.x + threadIdx.x;
    if (i < NN * 128) { Xb[i] = __float2bfloat16(X[i]); return; }
    i -= NN * 128;
    if (i < 128 * 2048) {
        int k = i / 2048, m = i - k * 2048;
        Wt1[(size_t)m * 128 + k] = __float2bfloat16(W1[i]);
        return;
    }
    i -= 128 * 2048;
    if (i < 64 * 1024) {
        int k = i / 1024, m = i - k * 1024;
        Wt2[(size_t)m * 64 + k] = __float2bfloat16(W2[i]);
    }
}

// ------- MFMA GEMM: XPB[n, M](bf16) = Xb[n, :K] @ Wt^T; fused alpha dots -------
template<int K, int M, int C>
__global__ __launch_bounds__(256) void k_gemm_mfma(
        const bf16* __restrict__ Xb, const bf16* __restrict__ Wt,
        const float* __restrict__ Asrc, const float* __restrict__ Adst,
        bf16* __restrict__ XPB, float* __restrict__ aS, float* __restrict__ aD) {
    constexpr int BM = 64, BN = 128;
    constexpr int KB = K * 2;            // LDS row bytes
    constexpr int NHB = BN / C;          // heads per block (2 or 4)
    constexpr int WPH = C / 32;          // waves per head  (2 or 1)
    __shared__ char lds[(BM + BN) * KB];
    __shared__ float sredS[4][BM], sredD[4][BM];
    char* lA = lds;
    char* lB = lds + BM * KB;

    const int tid = threadIdx.x;
    const int wv = tid >> 6, ln = tid & 63;
    const int lrow = ln & 15, lkb = ln >> 4;
    const int brow = blockIdx.x * BM;
    const int bcol = blockIdx.y * BN;

    #pragma unroll
    for (int c = 0; c < BM * K / 8 / 256; c++) {
        int it = c * 256 + tid;
        int r = it / (K / 8), kc = (it % (K / 8)) * 8;
        int node = brow + r;
        uint4 v = make_uint4(0u, 0u, 0u, 0u);
        if (node < NN) v = *reinterpret_cast<const uint4*>(&Xb[(size_t)node * K + kc]);
        *reinterpret_cast<uint4*>(lA + ((r * KB + kc * 2) ^ ((r & 7) << 4))) = v;
    }
    #pragma unroll
    for (int c = 0; c < BN * K / 8 / 256; c++) {
        int it = c * 256 + tid;
        int r = it / (K / 8), kc = (it % (K / 8)) * 8;
        uint4 v = *reinterpret_cast<const uint4*>(&Wt[(size_t)(bcol + r) * K + kc]);
        *reinterpret_cast<uint4*>(lB + ((r * KB + kc * 2) ^ ((r & 7) << 4))) = v;
    }
    __syncthreads();

    f32x4 acc[4][2];
    #pragma unroll
    for (int mi = 0; mi < 4; mi++)
        #pragma unroll
        for (int nj = 0; nj < 2; nj++) acc[mi][nj] = (f32x4){0.f, 0.f, 0.f, 0.f};

    #pragma unroll
    for (int ks = 0; ks < K / 32; ks++) {
        const int k0 = ks * 32 + lkb * 8;
        bf16x8 af[4], bfr[2];
        #pragma unroll
        for (int mi = 0; mi < 4; mi++) {
            int r = mi * 16 + lrow;
            af[mi] = *reinterpret_cast<const bf16x8*>(lA + ((r * KB + k0 * 2) ^ ((r & 7) << 4)));
        }
        #pragma unroll
        for (int nj = 0; nj < 2; nj++) {
            int r = wv * 32 + nj * 16 + lrow;
            bfr[nj] = *reinterpret_cast<const bf16x8*>(lB + ((r * KB + k0 * 2) ^ ((r & 7) << 4)));
        }
        #pragma unroll
        for (int mi = 0; mi < 4; mi++)
            #pragma unroll
            for (int nj = 0; nj < 2; nj++)
                acc[mi][nj] = __builtin_amdgcn_mfma_f32_16x16x32_bf16(af[mi], bfr[nj], acc[mi][nj], 0, 0, 0);
    }

    // epilogue: D col = lane&15, row = (lane>>4)*4 + reg  [m89]
    float ar0 = Asrc[bcol + wv * 32 + lrow];
    float ar1 = Asrc[bcol + wv * 32 + 16 + lrow];
    float ad0 = Adst[bcol + wv * 32 + lrow];
    float ad1 = Adst[bcol + wv * 32 + 16 + lrow];

    #pragma unroll
    for (int mi = 0; mi < 4; mi++) {
        #pragma unroll
        for (int r = 0; r < 4; r++) {
            int rowl = mi * 16 + lkb * 4 + r;
            int row = brow + rowl;
            if (row < NN) {
                XPB[(size_t)row * M + bcol + wv * 32 + lrow]      = __float2bfloat16(acc[mi][0][r]);
                XPB[(size_t)row * M + bcol + wv * 32 + 16 + lrow] = __float2bfloat16(acc[mi][1][r]);
            }
            float vs = acc[mi][0][r] * ar0 + acc[mi][1][r] * ar1;
            float vd = acc[mi][0][r] * ad0 + acc[mi][1][r] * ad1;
            vs += __shfl_xor(vs, 1); vd += __shfl_xor(vd, 1);
            vs += __shfl_xor(vs, 2); vd += __shfl_xor(vd, 2);
            vs += __shfl_xor(vs, 4); vd += __shfl_xor(vd, 4);
            vs += __shfl_xor(vs, 8); vd += __shfl_xor(vd, 8);
            if (lrow == 0) {
                sredS[wv][rowl] = vs;
                sredD[wv][rowl] = vd;
            }
        }
    }
    __syncthreads();
    if (tid < BM) {
        int node = brow + tid;
        if (node < NN) {
            #pragma unroll
            for (int hb = 0; hb < NHB; hb++) {
                float ss = 0.f, dd = 0.f;
                #pragma unroll
                for (int w = 0; w < WPH; w++) {
                    ss += sredS[hb * WPH + w][tid];
                    dd += sredD[hb * WPH + w][tid];
                }
                int h = bcol / C + hb;
                aS[node * NH + h] = ss;
                aD[node * NH + h] = dd;
            }
        }
    }
}

// ------- fused softmax+aggregation + head-mean + bias + ELU (+ bf16 z1 copy) -------
// single pass: constant-shift softmax (no per-node max; |scores| << SM_SHIFT).
template<int C, bool WZ>
__global__ void k_agg_fused(const bf16* __restrict__ XPB,
                            const float* __restrict__ aS, const float* __restrict__ aD,
                            const int* __restrict__ offs, const int* __restrict__ srcs,
                            const float* __restrict__ bias, float* __restrict__ out, int col0,
                            bf16* __restrict__ z1b) {
    const int M = NH * C;
    const int tid = threadIdx.x;        // blockDim = M/8
    const int node = blockIdx.x;
    const int m0 = tid * 8;
    const int h = m0 / C;
    const int beg = offs[node], end = offs[node + 1];
    const float ad = aD[node * NH + h];
    float acc[8];
    #pragma unroll
    for (int j = 0; j < 8; j++) acc[j] = 0.f;
    float ssum = 0.f;
    int i = beg;
    for (; i + 4 <= end; i += 4) {
        int s0 = srcs[i], s1 = srcs[i + 1], s2 = srcs[i + 2], s3 = srcs[i + 3];
        float c0 = aS[s0 * NH + h] + ad;
        float c1 = aS[s1 * NH + h] + ad;
        float c2 = aS[s2 * NH + h] + ad;
        float c3 = aS[s3 * NH + h] + ad;
        c0 = (c0 >= 0.f) ? c0 : LRELU_SLOPE * c0;
        c1 = (c1 >= 0.f) ? c1 : LRELU_SLOPE * c1;
        c2 = (c2 >= 0.f) ? c2 : LRELU_SLOPE * c2;
        c3 = (c3 >= 0.f) ? c3 : LRELU_SLOPE * c3;
        float p0 = expf(c0 - SM_SHIFT), p1 = expf(c1 - SM_SHIFT);
        float p2 = expf(c2 - SM_SHIFT), p3 = expf(c3 - SM_SHIFT);
        ssum += (p0 + p1) + (p2 + p3);
        float x0[8], x1[8], x2[8], x3[8];
        loadbf8(&XPB[(size_t)s0 * M + m0], x0);
        loadbf8(&XPB[(size_t)s1 * M + m0], x1);
        loadbf8(&XPB[(size_t)s2 * M + m0], x2);
        loadbf8(&XPB[(size_t)s3 * M + m0], x3);
        #pragma unroll
        for (int j = 0; j < 8; j++) {
            acc[j] = fmaf(p0, x0[j], acc[j]);
            acc[j] = fmaf(p1, x1[j], acc[j]);
            acc[j] = fmaf(p2, x2[j], acc[j]);
            acc[j] = fmaf(p3, x3[j], acc[j]);
        }
    }
    for (; i < end; i++) {
        int s = srcs[i];
        float c = aS[s * NH + h] + ad;
        c = (c >= 0.f) ? c : LRELU_SLOPE * c;
        float p = expf(c - SM_SHIFT);
        ssum += p;
        float xv[8];
        loadbf8(&XPB[(size_t)s * M + m0], xv);
        #pragma unroll
        for (int j = 0; j < 8; j++) acc[j] = fmaf(p, xv[j], acc[j]);
    }
    float r = 1.f / (ssum + SM_EPS);
    __shared__ float red[NH * C];
    #pragma unroll
    for (int j = 0; j < 8; j++) red[m0 + j] = acc[j] * r;
    __syncthreads();
    if (tid < C) {
        float sres = 0.f;
        #pragma unroll 8
        for (int hh = 0; hh < NH; hh++) sres += red[hh * C + tid];
        sres = sres * (1.0f / NH) + bias[tid];
        sres = (sres > 0.f) ? sres : expm1f(sres);
        out[(size_t)node * 96 + col0 + tid] = sres;
        if constexpr (WZ) z1b[(size_t)node * C + tid] = __float2bfloat16(sres);
    }
}

extern "C" void kernel_launch(void* const* d_in, const int* in_sizes, int n_in,
                              void* d_out, int out_size, void* d_ws, size_t ws_size,
                              hipStream_t stream) {
    const float* x   = (const float*)d_in[0];
    const int*   ei  = (const int*)d_in[1];
    const float* W1  = (const float*)d_in[2];
    const float* as1 = (const float*)d_in[3];
    const float* ad1 = (const float*)d_in[4];
    const float* b1  = (const float*)d_in[5];
    const float* W2  = (const float*)d_in[6];
    const float* as2 = (const float*)d_in[7];
    const float* ad2 = (const float*)d_in[8];
    const float* b2  = (const float*)d_in[9];
    float* out = (float*)d_out;

    char* w = (char*)d_ws;
    size_t off = 0;
    auto alloc = [&](size_t bytes) -> void* {
        void* p = w + off;
        off = (off + bytes + 255) & ~(size_t)255;
        return p;
    };
    bf16*  xpb    = (bf16*)alloc((size_t)NN * 2048 * 2);    // reused for layer2
    float* aS     = (float*)alloc((size_t)NN * NH * 4);
    float* aD     = (float*)alloc((size_t)NN * NH * 4);
    int*   deg    = (int*)alloc((size_t)NN * 4);
    int*   cursor = (int*)alloc((size_t)NN * 4);
    int*   offs   = (int*)alloc((size_t)(NN + 1) * 4);
    int*   srcs   = (int*)alloc((size_t)NE * 4);
    int*   srcv   = (int*)alloc((size_t)NE * 4);
    int*   dstv   = (int*)alloc((size_t)NE * 4);
    bf16*  Xb     = (bf16*)alloc((size_t)NN * 128 * 2);
    bf16*  Wt1    = (bf16*)alloc((size_t)2048 * 128 * 2);
    bf16*  Wt2    = (bf16*)alloc((size_t)1024 * 64 * 2);
    bf16*  z1b    = (bf16*)alloc((size_t)NN * 64 * 2);
    int*   eflag  = (int*)alloc(256);
    (void)ws_size; (void)in_sizes; (void)n_in; (void)out_size;

    // edges + CSR
    k_edge_detect<<<1, 64, 0, stream>>>((const unsigned int*)ei, eflag);
    k_edge_norm<<<(NE + 255) / 256, 256, 0, stream>>>(ei, eflag, srcv, dstv, deg);
    k_hist<<<NE / 256, 256, 0, stream>>>(dstv, deg);
    k_scan<<<1, 1024, 0, stream>>>(deg, offs, cursor);
    k_scatter<<<NE / 256, 256, 0, stream>>>(srcv, dstv, cursor, srcs);

    // bf16 operand prep (one kernel)
    k_prep<<<(NN * 128 + 128 * 2048 + 64 * 1024 + 255) / 256, 256, 0, stream>>>(
        x, Xb, W1, Wt1, W2, Wt2);

    // ---- Layer 1: K=128, C=64, M=2048 ----
    k_gemm_mfma<128, 2048, 64><<<dim3((NN + 63) / 64, 2048 / 128), 256, 0, stream>>>(
        Xb, Wt1, as1, ad1, xpb, aS, aD);
    k_agg_fused<64, true><<<NN, 256, 0, stream>>>(xpb, aS, aD, offs, srcs, b1, out, 0, z1b);

    // ---- Layer 2: K=64, C=32, M=1024 ----
    k_gemm_mfma<64, 1024, 32><<<dim3((NN + 63) / 64, 1024 / 128), 256, 0, stream>>>(
        z1b, Wt2, as2, ad2, xpb, aS, aD);
    k_agg_fused<32, false><<<NN, 128, 0, stream>>>(xpb, aS, aD, offs, srcs, b2, out, 64, nullptr);
}